// Round 1
// baseline (1441.087 us; speedup 1.0000x reference)
//
#include <hip/hip_runtime.h>
#include <math.h>

#define NN 100000
#define EE 3200000
#define EF 3300000
#define FE 7

// ---------------- ws layout (bytes) ----------------
// 0    : double ea_sum[8]
// 64   : double bn_sum[32]
// 320  : double bn_sumsq[32]
// 576  : float  ea_mean[8]
// 608  : float  wend[32]
// 736  : float  c0
// 1024 : int    offs[NN]          (degree -> exclusive scan -> inclusive-end after fill)
// then : xl[NN*32], xr[NN*32], h[NN*32] floats
// then : idx_csr[EF] int (src id if packed, edge id if compact)
// then : ea_csr[EF*8] float (packed mode only)

__global__ void k_ea_sum(const float* __restrict__ ea, double* __restrict__ ea_sum) {
    float acc[FE];
#pragma unroll
    for (int f = 0; f < FE; ++f) acc[f] = 0.f;
    int stride = gridDim.x * blockDim.x;
    for (int e = blockIdx.x * blockDim.x + threadIdx.x; e < EE; e += stride) {
        const float* r = ea + (size_t)e * FE;
#pragma unroll
        for (int f = 0; f < FE; ++f) acc[f] += r[f];
    }
#pragma unroll
    for (int f = 0; f < FE; ++f) {
        float v = acc[f];
        for (int o = 32; o > 0; o >>= 1) v += __shfl_down(v, o, 64);
        if ((threadIdx.x & 63) == 0) atomicAdd(&ea_sum[f], (double)v);
    }
}

__global__ void k_ea_mean(const double* __restrict__ ea_sum, float* __restrict__ ea_mean) {
    int f = threadIdx.x;
    if (f < 8) ea_mean[f] = (f < FE) ? (float)(ea_sum[f] / (double)EE) : 0.f;
}

__global__ void k_degree(const int* __restrict__ ei, int* __restrict__ offs) {
    int e = blockIdx.x * blockDim.x + threadIdx.x;
    if (e >= EF) return;
    int d = (e < EE) ? ei[EE + e] : (e - EE);
    atomicAdd(&offs[d], 1);
}

// single-workgroup in-place exclusive scan of offs[NN]
__global__ void k_scan(int* __restrict__ offs) {
    __shared__ int part[1024];
    int t = threadIdx.x;
    const int chunk = (NN + 1023) / 1024;
    int b = t * chunk;
    int e = b + chunk; if (e > NN) e = NN;
    int s = 0;
    for (int i = b; i < e; ++i) s += offs[i];
    part[t] = s;
    __syncthreads();
    for (int o = 1; o < 1024; o <<= 1) {
        int v = (t >= o) ? part[t - o] : 0;
        __syncthreads();
        part[t] += v;
        __syncthreads();
    }
    int run = (t > 0) ? part[t - 1] : 0;
    for (int i = b; i < e; ++i) { int d = offs[i]; offs[i] = run; run += d; }
}

template <bool PACKED>
__global__ void k_fill(const int* __restrict__ ei, const float* __restrict__ ea,
                       const float* __restrict__ ea_mean, int* __restrict__ offs,
                       int* __restrict__ idx_csr, float* __restrict__ ea_csr) {
    int e = blockIdx.x * blockDim.x + threadIdx.x;
    if (e >= EF) return;
    int d = (e < EE) ? ei[EE + e] : (e - EE);
    int pos = atomicAdd(&offs[d], 1);
    if (PACKED) {
        float a[8];
        int s;
        if (e < EE) {
            s = ei[e];
            const float* r = ea + (size_t)e * FE;
#pragma unroll
            for (int f = 0; f < FE; ++f) a[f] = r[f];
            a[7] = 0.f;
        } else {
            s = e - EE;
#pragma unroll
            for (int f = 0; f < 8; ++f) a[f] = ea_mean[f];
        }
        idx_csr[pos] = s;
        float4* dst = (float4*)(ea_csr + (size_t)pos * 8);
        dst[0] = make_float4(a[0], a[1], a[2], a[3]);
        dst[1] = make_float4(a[4], a[5], a[6], a[7]);
    } else {
        idx_csr[pos] = e;
    }
}

// xl = h@Wl+bl, xr = h@Wr+br  (one thread per (node,channel))
__global__ void k_xform(const float* __restrict__ h, int fin,
                        const float* __restrict__ Wl, const float* __restrict__ bl,
                        const float* __restrict__ Wr, const float* __restrict__ br,
                        float* __restrict__ xl, float* __restrict__ xr) {
    __shared__ float sWl[32 * 32], sWr[32 * 32], sb[64];
    for (int i = threadIdx.x; i < fin * 32; i += blockDim.x) { sWl[i] = Wl[i]; sWr[i] = Wr[i]; }
    if (threadIdx.x < 32) { sb[threadIdx.x] = bl[threadIdx.x]; sb[32 + threadIdx.x] = br[threadIdx.x]; }
    __syncthreads();
    int idx = blockIdx.x * blockDim.x + threadIdx.x;
    if (idx >= NN * 32) return;
    int n = idx >> 5, c = idx & 31;
    const float* hr = h + (size_t)n * fin;
    float al = sb[c], ar = sb[32 + c];
    for (int f = 0; f < fin; ++f) {
        float v = hr[f];
        al = fmaf(v, sWl[f * 32 + c], al);
        ar = fmaf(v, sWr[f * 32 + c], ar);
    }
    xl[idx] = al; xr[idx] = ar;
}

// GATv2 edge-softmax-aggregate: 8 lanes per dst node, 4 channels per lane,
// online softmax over the node's in-edges (CSR), zero atomics.
template <bool PACKED>
__global__ __launch_bounds__(256) void k_gat(
    const int* __restrict__ offs, const int* __restrict__ idx_csr,
    const float* __restrict__ ea_csr,
    const int* __restrict__ ei, const float* __restrict__ ea,
    const float* __restrict__ ea_mean,
    const float* __restrict__ xl, const float* __restrict__ xr,
    const float* __restrict__ We, const float* __restrict__ att,
    const float* __restrict__ bias, float* __restrict__ hout) {
    int t = blockIdx.x * blockDim.x + threadIdx.x;
    int node = t >> 3;
    if (node >= NN) return;
    int c0 = (t & 7) * 4;  // my 4 channels; head = c0>>3, att/bias flatten to [c0+j]

    float we[FE][4];
#pragma unroll
    for (int f = 0; f < FE; ++f)
#pragma unroll
        for (int j = 0; j < 4; ++j) we[f][j] = We[f * 32 + c0 + j];
    float at0 = att[c0], at1 = att[c0 + 1], at2 = att[c0 + 2], at3 = att[c0 + 3];
    float4 xrr = *(const float4*)(xr + (size_t)node * 32 + c0);
    float eam[FE];
    if (!PACKED) {
#pragma unroll
        for (int f = 0; f < FE; ++f) eam[f] = ea_mean[f];
    }

    int start = (node == 0) ? 0 : offs[node - 1];
    int end = offs[node];

    float mx = -INFINITY, sm = 0.f;
    float acc0 = 0.f, acc1 = 0.f, acc2 = 0.f, acc3 = 0.f;

    for (int p = start; p < end; ++p) {
        float a[8];
        int src;
        if (PACKED) {
            src = idx_csr[p];
            const float4* r = (const float4*)(ea_csr + (size_t)p * 8);
            float4 r0 = r[0], r1 = r[1];
            a[0] = r0.x; a[1] = r0.y; a[2] = r0.z; a[3] = r0.w;
            a[4] = r1.x; a[5] = r1.y; a[6] = r1.z; a[7] = r1.w;
        } else {
            int eid = idx_csr[p];
            if (eid < EE) {
                src = ei[eid];
                const float* r = ea + (size_t)eid * FE;
#pragma unroll
                for (int f = 0; f < FE; ++f) a[f] = r[f];
            } else {
                src = eid - EE;
#pragma unroll
                for (int f = 0; f < FE; ++f) a[f] = eam[f];
            }
        }
        float4 xs = *(const float4*)(xl + (size_t)src * 32 + c0);

        float ee0 = 0.f, ee1 = 0.f, ee2 = 0.f, ee3 = 0.f;
#pragma unroll
        for (int f = 0; f < FE; ++f) {
            ee0 = fmaf(a[f], we[f][0], ee0);
            ee1 = fmaf(a[f], we[f][1], ee1);
            ee2 = fmaf(a[f], we[f][2], ee2);
            ee3 = fmaf(a[f], we[f][3], ee3);
        }
        float v0 = xs.x + xrr.x + ee0;
        float v1 = xs.y + xrr.y + ee1;
        float v2 = xs.z + xrr.z + ee2;
        float v3 = xs.w + xrr.w + ee3;
        v0 = v0 > 0.f ? v0 : 0.2f * v0;
        v1 = v1 > 0.f ? v1 : 0.2f * v1;
        v2 = v2 > 0.f ? v2 : 0.2f * v2;
        v3 = v3 > 0.f ? v3 : 0.2f * v3;
        float pl = fmaf(v0, at0, fmaf(v1, at1, fmaf(v2, at2, v3 * at3)));
        // full head logit: pair lanes (same node, same head) combine
        float L = pl + __shfl_xor(pl, 1, 64);

        if (L <= mx) {
            float fct = __expf(L - mx);
            sm += fct;
            acc0 = fmaf(fct, xs.x, acc0);
            acc1 = fmaf(fct, xs.y, acc1);
            acc2 = fmaf(fct, xs.z, acc2);
            acc3 = fmaf(fct, xs.w, acc3);
        } else {
            float s = __expf(mx - L);  // first iter: exp(-inf)=0
            sm = fmaf(sm, s, 1.f);
            acc0 = fmaf(acc0, s, xs.x);
            acc1 = fmaf(acc1, s, xs.y);
            acc2 = fmaf(acc2, s, xs.z);
            acc3 = fmaf(acc3, s, xs.w);
            mx = L;
        }
    }
    float inv = 1.f / (sm + 1e-16f);
    float4 o;
    o.x = fmaf(acc0, inv, bias[c0 + 0]);
    o.y = fmaf(acc1, inv, bias[c0 + 1]);
    o.z = fmaf(acc2, inv, bias[c0 + 2]);
    o.w = fmaf(acc3, inv, bias[c0 + 3]);
    *(float4*)(hout + (size_t)node * 32 + c0) = o;
}

__global__ void k_bn_stats(const float* __restrict__ h, double* __restrict__ bn_sum,
                           double* __restrict__ bn_sumsq) {
    int c = threadIdx.x & 31;
    int row0 = (blockIdx.x * blockDim.x + threadIdx.x) >> 5;
    int rstride = (gridDim.x * blockDim.x) >> 5;
    float s = 0.f, s2 = 0.f;
    for (int n = row0; n < NN; n += rstride) {
        float v = h[(size_t)n * 32 + c];
        s += v;
        s2 = fmaf(v, v, s2);
    }
    s += __shfl_down(s, 32, 64);
    s2 += __shfl_down(s2, 32, 64);
    __shared__ float ls[4][32], ls2[4][32];
    int w = threadIdx.x >> 6;
    if ((threadIdx.x & 63) < 32) { ls[w][c] = s; ls2[w][c] = s2; }
    __syncthreads();
    if (threadIdx.x < 32) {
        float tsum = 0.f, tsq = 0.f;
        for (int i = 0; i < 4; ++i) { tsum += ls[i][threadIdx.x]; tsq += ls2[i][threadIdx.x]; }
        atomicAdd(&bn_sum[threadIdx.x], (double)tsum);
        atomicAdd(&bn_sumsq[threadIdx.x], (double)tsq);
    }
}

__global__ void k_bn_apply(float* __restrict__ h, const double* __restrict__ bn_sum,
                           const double* __restrict__ bn_sumsq,
                           const float* __restrict__ gamma, const float* __restrict__ beta) {
    int idx = blockIdx.x * blockDim.x + threadIdx.x;
    if (idx >= NN * 32) return;
    int c = idx & 31;
    double mu = bn_sum[c] * (1.0 / NN);
    double var = bn_sumsq[c] * (1.0 / NN) - mu * mu;
    float scale = gamma[c] * (float)(1.0 / sqrt(var + 1e-5));
    float y = (float)((double)h[idx] - mu) * scale + beta[c];
    h[idx] = y > 0.f ? y : 0.01f * y;
}

// wend = Wreg@Wend, c0 = breg.Wend + bend  (linear∘linear collapse)
__global__ void k_wend(const float* __restrict__ Wreg, const float* __restrict__ breg,
                       const float* __restrict__ Wend, const float* __restrict__ bend,
                       float* __restrict__ wend, float* __restrict__ c0v) {
    int t = threadIdx.x;
    if (t < 32) {
        float s = 0.f;
        for (int k = 0; k < 500; ++k) s = fmaf(Wreg[t * 500 + k], Wend[k], s);
        wend[t] = s;
    } else if (t == 32) {
        float s = 0.f;
        for (int k = 0; k < 500; ++k) s = fmaf(breg[k], Wend[k], s);
        *c0v = s + bend[0];
    }
}

__global__ void k_out(const float* __restrict__ h, const float* __restrict__ wend,
                      const float* __restrict__ c0v, float* __restrict__ out) {
    int n = blockIdx.x * blockDim.x + threadIdx.x;
    if (n >= NN) return;
    const float* r = h + (size_t)n * 32;
    float s = *c0v;
#pragma unroll
    for (int c = 0; c < 32; ++c) {
        float v = r[c];
        v = v > 0.f ? v : 0.01f * v;
        s = fmaf(v, wend[c], s);
    }
    out[n] = s;
}

extern "C" void kernel_launch(void* const* d_in, const int* in_sizes, int n_in,
                              void* d_out, int out_size, void* d_ws, size_t ws_size,
                              hipStream_t stream) {
    (void)in_sizes; (void)n_in; (void)out_size;
    const float* x    = (const float*)d_in[0];
    const int*   ei   = (const int*)d_in[1];
    const float* ea   = (const float*)d_in[2];
    const float* Wl1  = (const float*)d_in[3];
    const float* bl1  = (const float*)d_in[4];
    const float* Wr1  = (const float*)d_in[5];
    const float* br1  = (const float*)d_in[6];
    const float* We1  = (const float*)d_in[7];
    const float* att1 = (const float*)d_in[8];
    const float* b1   = (const float*)d_in[9];
    const float* Wl2  = (const float*)d_in[10];
    const float* bl2  = (const float*)d_in[11];
    const float* Wr2  = (const float*)d_in[12];
    const float* br2  = (const float*)d_in[13];
    const float* We2  = (const float*)d_in[14];
    const float* att2 = (const float*)d_in[15];
    const float* b2   = (const float*)d_in[16];
    const float* gamma= (const float*)d_in[17];
    const float* beta = (const float*)d_in[18];
    const float* Wreg = (const float*)d_in[19];
    const float* breg = (const float*)d_in[20];
    const float* Wend = (const float*)d_in[21];
    const float* bend = (const float*)d_in[22];
    float* out = (float*)d_out;

    char* w = (char*)d_ws;
    double* ea_sum   = (double*)(w + 0);
    double* bn_sum   = (double*)(w + 64);
    double* bn_sumsq = (double*)(w + 320);
    float*  ea_mean  = (float*)(w + 576);
    float*  wend     = (float*)(w + 608);
    float*  c0v      = (float*)(w + 736);
    size_t o = 1024;
    int* offs = (int*)(w + o); o += ((size_t)NN * 4 + 255) & ~(size_t)255;
    float* xl = (float*)(w + o); o += (size_t)NN * 32 * 4;
    float* xr = (float*)(w + o); o += (size_t)NN * 32 * 4;
    float* hb = (float*)(w + o); o += (size_t)NN * 32 * 4;
    int* idx_csr = (int*)(w + o); o += ((size_t)EF * 4 + 255) & ~(size_t)255;
    float* ea_csr = (float*)(w + o); o += (size_t)EF * 8 * 4;
    bool packed = (ws_size >= o);

    hipMemsetAsync(w, 0, 1024, stream);
    hipMemsetAsync(offs, 0, (size_t)NN * 4, stream);

    const int ebl = (EF + 255) / 256;
    k_ea_sum<<<1024, 256, 0, stream>>>(ea, ea_sum);
    k_ea_mean<<<1, 64, 0, stream>>>(ea_sum, ea_mean);
    k_degree<<<ebl, 256, 0, stream>>>(ei, offs);
    k_scan<<<1, 1024, 0, stream>>>(offs);
    if (packed) k_fill<true><<<ebl, 256, 0, stream>>>(ei, ea, ea_mean, offs, idx_csr, ea_csr);
    else        k_fill<false><<<ebl, 256, 0, stream>>>(ei, ea, ea_mean, offs, idx_csr, ea_csr);
    k_wend<<<1, 64, 0, stream>>>(Wreg, breg, Wend, bend, wend, c0v);

    const int xbl = (NN * 32 + 255) / 256;
    const int gbl = (NN * 8 + 255) / 256;

    // layer 1
    k_xform<<<xbl, 256, 0, stream>>>(x, 2, Wl1, bl1, Wr1, br1, xl, xr);
    if (packed) k_gat<true><<<gbl, 256, 0, stream>>>(offs, idx_csr, ea_csr, ei, ea, ea_mean, xl, xr, We1, att1, b1, hb);
    else        k_gat<false><<<gbl, 256, 0, stream>>>(offs, idx_csr, ea_csr, ei, ea, ea_mean, xl, xr, We1, att1, b1, hb);

    // 2x (BN -> lrelu -> layer2)
    for (int it = 0; it < 2; ++it) {
        hipMemsetAsync(w + 64, 0, 512, stream);
        k_bn_stats<<<256, 256, 0, stream>>>(hb, bn_sum, bn_sumsq);
        k_bn_apply<<<xbl, 256, 0, stream>>>(hb, bn_sum, bn_sumsq, gamma, beta);
        k_xform<<<xbl, 256, 0, stream>>>(hb, 32, Wl2, bl2, Wr2, br2, xl, xr);
        if (packed) k_gat<true><<<gbl, 256, 0, stream>>>(offs, idx_csr, ea_csr, ei, ea, ea_mean, xl, xr, We2, att2, b2, hb);
        else        k_gat<false><<<gbl, 256, 0, stream>>>(offs, idx_csr, ea_csr, ei, ea, ea_mean, xl, xr, We2, att2, b2, hb);
    }

    k_out<<<(NN + 255) / 256, 256, 0, stream>>>(hb, wend, c0v, out);
}

// Round 2
// 1103.678 us; speedup vs baseline: 1.3057x; 1.3057x over previous
//
#include <hip/hip_runtime.h>
#include <math.h>

#define NN 100000
#define EE 3200000
#define EF 3300000
#define FE 7

// ---------------- ws layout (bytes) ----------------
// 0    : double ea_sum[8]
// 64   : double bn_sum[32]
// 320  : double bn_sumsq[32]
// 576  : float  ea_mean[8]
// 608  : float  wend[32]
// 736  : float  c0
// 1024 : int    offs[NN]          (degree -> exclusive scan -> inclusive-end after fill)
// then : xl[NN*32], xr[NN*32], h[NN*32] floats
// then : idx_csr[EF] int (src id if packed, edge id if compact)
// then : ea_csr[EF*8] float (packed mode only)

// Block-reduced mean accumulation: 7 double atomics per BLOCK (was per wave ->
// 28K same-line atomics = 369us serialized; see round-1 post-mortem).
__global__ void k_ea_sum(const float* __restrict__ ea, double* __restrict__ ea_sum) {
    float acc[FE];
#pragma unroll
    for (int f = 0; f < FE; ++f) acc[f] = 0.f;
    int stride = gridDim.x * blockDim.x;
    for (int e = blockIdx.x * blockDim.x + threadIdx.x; e < EE; e += stride) {
        const float* r = ea + (size_t)e * FE;
#pragma unroll
        for (int f = 0; f < FE; ++f) acc[f] += r[f];
    }
    __shared__ float part[4][FE];
    int wave = threadIdx.x >> 6;
#pragma unroll
    for (int f = 0; f < FE; ++f) {
        float v = acc[f];
        for (int o = 32; o > 0; o >>= 1) v += __shfl_down(v, o, 64);
        if ((threadIdx.x & 63) == 0) part[wave][f] = v;
    }
    __syncthreads();
    if (threadIdx.x < FE) {
        float s = part[0][threadIdx.x] + part[1][threadIdx.x] +
                  part[2][threadIdx.x] + part[3][threadIdx.x];
        atomicAdd(&ea_sum[threadIdx.x], (double)s);
    }
}

__global__ void k_ea_mean(const double* __restrict__ ea_sum, float* __restrict__ ea_mean) {
    int f = threadIdx.x;
    if (f < 8) ea_mean[f] = (f < FE) ? (float)(ea_sum[f] / (double)EE) : 0.f;
}

__global__ void k_degree(const int* __restrict__ ei, int* __restrict__ offs) {
    int e = blockIdx.x * blockDim.x + threadIdx.x;
    if (e >= EF) return;
    int d = (e < EE) ? ei[EE + e] : (e - EE);
    atomicAdd(&offs[d], 1);
}

// single-workgroup in-place exclusive scan of offs[NN]
__global__ void k_scan(int* __restrict__ offs) {
    __shared__ int part[1024];
    int t = threadIdx.x;
    const int chunk = (NN + 1023) / 1024;
    int b = t * chunk;
    int e = b + chunk; if (e > NN) e = NN;
    int s = 0;
    for (int i = b; i < e; ++i) s += offs[i];
    part[t] = s;
    __syncthreads();
    for (int o = 1; o < 1024; o <<= 1) {
        int v = (t >= o) ? part[t - o] : 0;
        __syncthreads();
        part[t] += v;
        __syncthreads();
    }
    int run = (t > 0) ? part[t - 1] : 0;
    for (int i = b; i < e; ++i) { int d = offs[i]; offs[i] = run; run += d; }
}

template <bool PACKED>
__global__ void k_fill(const int* __restrict__ ei, const float* __restrict__ ea,
                       const float* __restrict__ ea_mean, int* __restrict__ offs,
                       int* __restrict__ idx_csr, float* __restrict__ ea_csr) {
    int e = blockIdx.x * blockDim.x + threadIdx.x;
    if (e >= EF) return;
    int d = (e < EE) ? ei[EE + e] : (e - EE);
    int pos = atomicAdd(&offs[d], 1);
    if (PACKED) {
        float a[8];
        int s;
        if (e < EE) {
            s = ei[e];
            const float* r = ea + (size_t)e * FE;
#pragma unroll
            for (int f = 0; f < FE; ++f) a[f] = r[f];
            a[7] = 0.f;
        } else {
            s = e - EE;
#pragma unroll
            for (int f = 0; f < 8; ++f) a[f] = ea_mean[f];
        }
        idx_csr[pos] = s;
        float4* dst = (float4*)(ea_csr + (size_t)pos * 8);
        dst[0] = make_float4(a[0], a[1], a[2], a[3]);
        dst[1] = make_float4(a[4], a[5], a[6], a[7]);
    } else {
        idx_csr[pos] = e;
    }
}

// xl = act(BN(h))@Wl+bl, xr likewise. BN+LeakyReLU fused (replaces k_bn_apply).
template <int FIN, bool BN>
__global__ void k_xform(const float* __restrict__ h,
                        const float* __restrict__ Wl, const float* __restrict__ bl,
                        const float* __restrict__ Wr, const float* __restrict__ br,
                        const double* __restrict__ bn_sum, const double* __restrict__ bn_sumsq,
                        const float* __restrict__ gamma, const float* __restrict__ beta,
                        float* __restrict__ xl, float* __restrict__ xr) {
    __shared__ float sWl[FIN * 32], sWr[FIN * 32], sb[64];
    __shared__ float smu[FIN > 0 ? FIN : 1], ssc[FIN > 0 ? FIN : 1], sbe[FIN > 0 ? FIN : 1];
    for (int i = threadIdx.x; i < FIN * 32; i += blockDim.x) { sWl[i] = Wl[i]; sWr[i] = Wr[i]; }
    if (threadIdx.x < 32) { sb[threadIdx.x] = bl[threadIdx.x]; sb[32 + threadIdx.x] = br[threadIdx.x]; }
    if (BN && threadIdx.x < FIN) {
        int f = threadIdx.x;
        double mu = bn_sum[f] * (1.0 / NN);
        double var = bn_sumsq[f] * (1.0 / NN) - mu * mu;
        smu[f] = (float)mu;
        ssc[f] = gamma[f] * (float)(1.0 / sqrt(var + 1e-5));
        sbe[f] = beta[f];
    }
    __syncthreads();
    int idx = blockIdx.x * blockDim.x + threadIdx.x;
    if (idx >= NN * 32) return;
    int n = idx >> 5, c = idx & 31;
    const float* hr = h + (size_t)n * FIN;
    float al = sb[c], ar = sb[32 + c];
#pragma unroll
    for (int f = 0; f < FIN; ++f) {
        float v = hr[f];
        if (BN) {
            v = fmaf(v - smu[f], ssc[f], sbe[f]);
            v = v > 0.f ? v : 0.01f * v;
        }
        al = fmaf(v, sWl[f * 32 + c], al);
        ar = fmaf(v, sWr[f * 32 + c], ar);
    }
    xl[idx] = al; xr[idx] = ar;
}

// GATv2 edge-softmax-aggregate: 8 lanes per dst node, 4 channels per lane,
// online softmax over the node's in-edges (CSR), zero atomics.
template <bool PACKED>
__global__ __launch_bounds__(256) void k_gat(
    const int* __restrict__ offs, const int* __restrict__ idx_csr,
    const float* __restrict__ ea_csr,
    const int* __restrict__ ei, const float* __restrict__ ea,
    const float* __restrict__ ea_mean,
    const float* __restrict__ xl, const float* __restrict__ xr,
    const float* __restrict__ We, const float* __restrict__ att,
    const float* __restrict__ bias, float* __restrict__ hout) {
    int t = blockIdx.x * blockDim.x + threadIdx.x;
    int node = t >> 3;
    if (node >= NN) return;
    int c0 = (t & 7) * 4;  // my 4 channels; head = c0>>3, att/bias flatten to [c0+j]

    float we[FE][4];
#pragma unroll
    for (int f = 0; f < FE; ++f)
#pragma unroll
        for (int j = 0; j < 4; ++j) we[f][j] = We[f * 32 + c0 + j];
    float at0 = att[c0], at1 = att[c0 + 1], at2 = att[c0 + 2], at3 = att[c0 + 3];
    float4 xrr = *(const float4*)(xr + (size_t)node * 32 + c0);
    float eam[FE];
    if (!PACKED) {
#pragma unroll
        for (int f = 0; f < FE; ++f) eam[f] = ea_mean[f];
    }

    int start = (node == 0) ? 0 : offs[node - 1];
    int end = offs[node];

    float mx = -INFINITY, sm = 0.f;
    float acc0 = 0.f, acc1 = 0.f, acc2 = 0.f, acc3 = 0.f;

    for (int p = start; p < end; ++p) {
        float a[8];
        int src;
        if (PACKED) {
            src = idx_csr[p];
            const float4* r = (const float4*)(ea_csr + (size_t)p * 8);
            float4 r0 = r[0], r1 = r[1];
            a[0] = r0.x; a[1] = r0.y; a[2] = r0.z; a[3] = r0.w;
            a[4] = r1.x; a[5] = r1.y; a[6] = r1.z; a[7] = r1.w;
        } else {
            int eid = idx_csr[p];
            if (eid < EE) {
                src = ei[eid];
                const float* r = ea + (size_t)eid * FE;
#pragma unroll
                for (int f = 0; f < FE; ++f) a[f] = r[f];
            } else {
                src = eid - EE;
#pragma unroll
                for (int f = 0; f < FE; ++f) a[f] = eam[f];
            }
        }
        float4 xs = *(const float4*)(xl + (size_t)src * 32 + c0);

        float ee0 = 0.f, ee1 = 0.f, ee2 = 0.f, ee3 = 0.f;
#pragma unroll
        for (int f = 0; f < FE; ++f) {
            ee0 = fmaf(a[f], we[f][0], ee0);
            ee1 = fmaf(a[f], we[f][1], ee1);
            ee2 = fmaf(a[f], we[f][2], ee2);
            ee3 = fmaf(a[f], we[f][3], ee3);
        }
        float v0 = xs.x + xrr.x + ee0;
        float v1 = xs.y + xrr.y + ee1;
        float v2 = xs.z + xrr.z + ee2;
        float v3 = xs.w + xrr.w + ee3;
        v0 = v0 > 0.f ? v0 : 0.2f * v0;
        v1 = v1 > 0.f ? v1 : 0.2f * v1;
        v2 = v2 > 0.f ? v2 : 0.2f * v2;
        v3 = v3 > 0.f ? v3 : 0.2f * v3;
        float pl = fmaf(v0, at0, fmaf(v1, at1, fmaf(v2, at2, v3 * at3)));
        // full head logit: pair lanes (same node, same head) combine
        float L = pl + __shfl_xor(pl, 1, 64);

        if (L <= mx) {
            float fct = __expf(L - mx);
            sm += fct;
            acc0 = fmaf(fct, xs.x, acc0);
            acc1 = fmaf(fct, xs.y, acc1);
            acc2 = fmaf(fct, xs.z, acc2);
            acc3 = fmaf(fct, xs.w, acc3);
        } else {
            float s = __expf(mx - L);  // first iter: exp(-inf)=0
            sm = fmaf(sm, s, 1.f);
            acc0 = fmaf(acc0, s, xs.x);
            acc1 = fmaf(acc1, s, xs.y);
            acc2 = fmaf(acc2, s, xs.z);
            acc3 = fmaf(acc3, s, xs.w);
            mx = L;
        }
    }
    float inv = 1.f / (sm + 1e-16f);
    float4 o;
    o.x = fmaf(acc0, inv, bias[c0 + 0]);
    o.y = fmaf(acc1, inv, bias[c0 + 1]);
    o.z = fmaf(acc2, inv, bias[c0 + 2]);
    o.w = fmaf(acc3, inv, bias[c0 + 3]);
    *(float4*)(hout + (size_t)node * 32 + c0) = o;
}

__global__ void k_bn_stats(const float* __restrict__ h, double* __restrict__ bn_sum,
                           double* __restrict__ bn_sumsq) {
    int c = threadIdx.x & 31;
    int row0 = (blockIdx.x * blockDim.x + threadIdx.x) >> 5;
    int rstride = (gridDim.x * blockDim.x) >> 5;
    float s = 0.f, s2 = 0.f;
    for (int n = row0; n < NN; n += rstride) {
        float v = h[(size_t)n * 32 + c];
        s += v;
        s2 = fmaf(v, v, s2);
    }
    s += __shfl_down(s, 32, 64);
    s2 += __shfl_down(s2, 32, 64);
    __shared__ float ls[4][32], ls2[4][32];
    int w = threadIdx.x >> 6;
    if ((threadIdx.x & 63) < 32) { ls[w][c] = s; ls2[w][c] = s2; }
    __syncthreads();
    if (threadIdx.x < 32) {
        float tsum = 0.f, tsq = 0.f;
        for (int i = 0; i < 4; ++i) { tsum += ls[i][threadIdx.x]; tsq += ls2[i][threadIdx.x]; }
        atomicAdd(&bn_sum[threadIdx.x], (double)tsum);
        atomicAdd(&bn_sumsq[threadIdx.x], (double)tsq);
    }
}

// wend = Wreg@Wend, c0 = breg.Wend + bend  (linear∘linear collapse)
__global__ void k_wend(const float* __restrict__ Wreg, const float* __restrict__ breg,
                       const float* __restrict__ Wend, const float* __restrict__ bend,
                       float* __restrict__ wend, float* __restrict__ c0v) {
    int t = threadIdx.x;
    if (t < 32) {
        float s = 0.f;
        for (int k = 0; k < 500; ++k) s = fmaf(Wreg[t * 500 + k], Wend[k], s);
        wend[t] = s;
    } else if (t == 32) {
        float s = 0.f;
        for (int k = 0; k < 500; ++k) s = fmaf(breg[k], Wend[k], s);
        *c0v = s + bend[0];
    }
}

__global__ void k_out(const float* __restrict__ h, const float* __restrict__ wend,
                      const float* __restrict__ c0v, float* __restrict__ out) {
    int n = blockIdx.x * blockDim.x + threadIdx.x;
    if (n >= NN) return;
    const float* r = h + (size_t)n * 32;
    float s = *c0v;
#pragma unroll
    for (int c = 0; c < 32; ++c) {
        float v = r[c];
        v = v > 0.f ? v : 0.01f * v;
        s = fmaf(v, wend[c], s);
    }
    out[n] = s;
}

extern "C" void kernel_launch(void* const* d_in, const int* in_sizes, int n_in,
                              void* d_out, int out_size, void* d_ws, size_t ws_size,
                              hipStream_t stream) {
    (void)in_sizes; (void)n_in; (void)out_size;
    const float* x    = (const float*)d_in[0];
    const int*   ei   = (const int*)d_in[1];
    const float* ea   = (const float*)d_in[2];
    const float* Wl1  = (const float*)d_in[3];
    const float* bl1  = (const float*)d_in[4];
    const float* Wr1  = (const float*)d_in[5];
    const float* br1  = (const float*)d_in[6];
    const float* We1  = (const float*)d_in[7];
    const float* att1 = (const float*)d_in[8];
    const float* b1   = (const float*)d_in[9];
    const float* Wl2  = (const float*)d_in[10];
    const float* bl2  = (const float*)d_in[11];
    const float* Wr2  = (const float*)d_in[12];
    const float* br2  = (const float*)d_in[13];
    const float* We2  = (const float*)d_in[14];
    const float* att2 = (const float*)d_in[15];
    const float* b2   = (const float*)d_in[16];
    const float* gamma= (const float*)d_in[17];
    const float* beta = (const float*)d_in[18];
    const float* Wreg = (const float*)d_in[19];
    const float* breg = (const float*)d_in[20];
    const float* Wend = (const float*)d_in[21];
    const float* bend = (const float*)d_in[22];
    float* out = (float*)d_out;

    char* w = (char*)d_ws;
    double* ea_sum   = (double*)(w + 0);
    double* bn_sum   = (double*)(w + 64);
    double* bn_sumsq = (double*)(w + 320);
    float*  ea_mean  = (float*)(w + 576);
    float*  wend     = (float*)(w + 608);
    float*  c0v      = (float*)(w + 736);
    size_t o = 1024;
    int* offs = (int*)(w + o); o += ((size_t)NN * 4 + 255) & ~(size_t)255;
    float* xl = (float*)(w + o); o += (size_t)NN * 32 * 4;
    float* xr = (float*)(w + o); o += (size_t)NN * 32 * 4;
    float* hb = (float*)(w + o); o += (size_t)NN * 32 * 4;
    int* idx_csr = (int*)(w + o); o += ((size_t)EF * 4 + 255) & ~(size_t)255;
    float* ea_csr = (float*)(w + o); o += (size_t)EF * 8 * 4;
    bool packed = (ws_size >= o);

    hipMemsetAsync(w, 0, 1024, stream);
    hipMemsetAsync(offs, 0, (size_t)NN * 4, stream);

    const int ebl = (EF + 255) / 256;
    k_ea_sum<<<256, 256, 0, stream>>>(ea, ea_sum);
    k_ea_mean<<<1, 64, 0, stream>>>(ea_sum, ea_mean);
    k_degree<<<ebl, 256, 0, stream>>>(ei, offs);
    k_scan<<<1, 1024, 0, stream>>>(offs);
    if (packed) k_fill<true><<<ebl, 256, 0, stream>>>(ei, ea, ea_mean, offs, idx_csr, ea_csr);
    else        k_fill<false><<<ebl, 256, 0, stream>>>(ei, ea, ea_mean, offs, idx_csr, ea_csr);
    k_wend<<<1, 64, 0, stream>>>(Wreg, breg, Wend, bend, wend, c0v);

    const int xbl = (NN * 32 + 255) / 256;
    const int gbl = (NN * 8 + 255) / 256;

    // layer 1 (no BN on raw input x)
    k_xform<2, false><<<xbl, 256, 0, stream>>>(x, Wl1, bl1, Wr1, br1,
                                               bn_sum, bn_sumsq, gamma, beta, xl, xr);
    if (packed) k_gat<true><<<gbl, 256, 0, stream>>>(offs, idx_csr, ea_csr, ei, ea, ea_mean, xl, xr, We1, att1, b1, hb);
    else        k_gat<false><<<gbl, 256, 0, stream>>>(offs, idx_csr, ea_csr, ei, ea, ea_mean, xl, xr, We1, att1, b1, hb);

    // 2x (BN-stats -> fused BN+lrelu+xform -> layer2 GAT)
    for (int it = 0; it < 2; ++it) {
        hipMemsetAsync(w + 64, 0, 512, stream);
        k_bn_stats<<<256, 256, 0, stream>>>(hb, bn_sum, bn_sumsq);
        k_xform<32, true><<<xbl, 256, 0, stream>>>(hb, Wl2, bl2, Wr2, br2,
                                                   bn_sum, bn_sumsq, gamma, beta, xl, xr);
        if (packed) k_gat<true><<<gbl, 256, 0, stream>>>(offs, idx_csr, ea_csr, ei, ea, ea_mean, xl, xr, We2, att2, b2, hb);
        else        k_gat<false><<<gbl, 256, 0, stream>>>(offs, idx_csr, ea_csr, ei, ea, ea_mean, xl, xr, We2, att2, b2, hb);
    }

    k_out<<<(NN + 255) / 256, 256, 0, stream>>>(hb, wend, c0v, out);
}

// Round 5
// 1064.580 us; speedup vs baseline: 1.3537x; 1.0367x over previous
//
#include <hip/hip_runtime.h>
#include <hip/hip_fp16.h>
#include <math.h>

#define NN 100000
#define EE 3200000
#define EF 3300000
#define FE 7

// ---------------- ws layout (bytes) ----------------
// 0    : double ea_sum[8]
// 64   : double bn_sum[32]
// 320  : double bn_sumsq[32]
// 576  : float  ea_mean[8]
// 608  : float  wend[32]
// 736  : float  c0
// 1024 : int    offs[NN]          (degree -> exclusive scan -> inclusive-end after fill)
// then : xl[NN*32] half, xr[NN*32] float, h[NN*32] float
// then : rec[EF*8] float  ({src-as-float, a0..a6} 32B records, CSR order)

__global__ void k_ea_sum(const float* __restrict__ ea, double* __restrict__ ea_sum) {
    float acc[FE];
#pragma unroll
    for (int f = 0; f < FE; ++f) acc[f] = 0.f;
    int stride = gridDim.x * blockDim.x;
    for (int e = blockIdx.x * blockDim.x + threadIdx.x; e < EE; e += stride) {
        const float* r = ea + (size_t)e * FE;
#pragma unroll
        for (int f = 0; f < FE; ++f) acc[f] += r[f];
    }
    __shared__ float part[4][FE];
    int wave = threadIdx.x >> 6;
#pragma unroll
    for (int f = 0; f < FE; ++f) {
        float v = acc[f];
        for (int o = 32; o > 0; o >>= 1) v += __shfl_down(v, o, 64);
        if ((threadIdx.x & 63) == 0) part[wave][f] = v;
    }
    __syncthreads();
    if (threadIdx.x < FE) {
        float s = part[0][threadIdx.x] + part[1][threadIdx.x] +
                  part[2][threadIdx.x] + part[3][threadIdx.x];
        atomicAdd(&ea_sum[threadIdx.x], (double)s);
    }
}

__global__ void k_ea_mean(const double* __restrict__ ea_sum, float* __restrict__ ea_mean) {
    int f = threadIdx.x;
    if (f < 8) ea_mean[f] = (f < FE) ? (float)(ea_sum[f] / (double)EE) : 0.f;
}

__global__ void k_degree(const int* __restrict__ ei, int* __restrict__ offs) {
    int e = blockIdx.x * blockDim.x + threadIdx.x;
    if (e >= EF) return;
    int d = (e < EE) ? ei[EE + e] : (e - EE);
    atomicAdd(&offs[d], 1);
}

// single-workgroup in-place exclusive scan of offs[NN]
__global__ void k_scan(int* __restrict__ offs) {
    __shared__ int part[1024];
    int t = threadIdx.x;
    const int chunk = (NN + 1023) / 1024;
    int b = t * chunk;
    int e = b + chunk; if (e > NN) e = NN;
    int s = 0;
    for (int i = b; i < e; ++i) s += offs[i];
    part[t] = s;
    __syncthreads();
    for (int o = 1; o < 1024; o <<= 1) {
        int v = (t >= o) ? part[t - o] : 0;
        __syncthreads();
        part[t] += v;
        __syncthreads();
    }
    int run = (t > 0) ? part[t - 1] : 0;
    for (int i = b; i < e; ++i) { int d = offs[i]; offs[i] = run; run += d; }
}

// single merged 32B record per edge: {src-as-float, a0..a6}; one scatter stream
__global__ void k_fill(const int* __restrict__ ei, const float* __restrict__ ea,
                       const float* __restrict__ ea_mean, int* __restrict__ offs,
                       float4* __restrict__ rec) {
    int e = blockIdx.x * blockDim.x + threadIdx.x;
    if (e >= EF) return;
    int d = (e < EE) ? ei[EE + e] : (e - EE);
    int pos = atomicAdd(&offs[d], 1);
    float a[FE];
    int s;
    if (e < EE) {
        s = ei[e];
        const float* r = ea + (size_t)e * FE;
#pragma unroll
        for (int f = 0; f < FE; ++f) a[f] = r[f];
    } else {
        s = e - EE;
#pragma unroll
        for (int f = 0; f < FE; ++f) a[f] = ea_mean[f];
    }
    rec[(size_t)pos * 2]     = make_float4(__int_as_float(s), a[0], a[1], a[2]);
    rec[(size_t)pos * 2 + 1] = make_float4(a[3], a[4], a[5], a[6]);
}

// xl = act(BN(h))@Wl+bl (stored fp16), xr = act(BN(h))@Wr+br (fp32).
template <int FIN, bool BN>
__global__ void k_xform(const float* __restrict__ h,
                        const float* __restrict__ Wl, const float* __restrict__ bl,
                        const float* __restrict__ Wr, const float* __restrict__ br,
                        const double* __restrict__ bn_sum, const double* __restrict__ bn_sumsq,
                        const float* __restrict__ gamma, const float* __restrict__ beta,
                        __half* __restrict__ xl, float* __restrict__ xr) {
    __shared__ float sWl[FIN * 32], sWr[FIN * 32], sb[64];
    __shared__ float smu[FIN], ssc[FIN], sbe[FIN];
    for (int i = threadIdx.x; i < FIN * 32; i += blockDim.x) { sWl[i] = Wl[i]; sWr[i] = Wr[i]; }
    if (threadIdx.x < 32) { sb[threadIdx.x] = bl[threadIdx.x]; sb[32 + threadIdx.x] = br[threadIdx.x]; }
    if (BN && threadIdx.x < FIN) {
        int f = threadIdx.x;
        double mu = bn_sum[f] * (1.0 / NN);
        double var = bn_sumsq[f] * (1.0 / NN) - mu * mu;
        smu[f] = (float)mu;
        ssc[f] = gamma[f] * (float)(1.0 / sqrt(var + 1e-5));
        sbe[f] = beta[f];
    }
    __syncthreads();
    int idx = blockIdx.x * blockDim.x + threadIdx.x;
    if (idx >= NN * 32) return;
    int n = idx >> 5, c = idx & 31;
    const float* hr = h + (size_t)n * FIN;
    float al = sb[c], ar = sb[32 + c];
#pragma unroll
    for (int f = 0; f < FIN; ++f) {
        float v = hr[f];
        if (BN) {
            v = fmaf(v - smu[f], ssc[f], sbe[f]);
            v = v > 0.f ? v : 0.01f * v;
        }
        al = fmaf(v, sWl[f * 32 + c], al);
        ar = fmaf(v, sWr[f * 32 + c], ar);
    }
    xl[idx] = __float2half(al);
    xr[idx] = ar;
}

// GATv2 edge-softmax-aggregate: 8 lanes per dst node, 4 channels per lane.
// No running max (logits bounded |L| <~ 40 << 88, softmax is shift-invariant):
// branchless body, no serial rescale chain. xl gathered as fp16 (8B/lane).
__global__ __launch_bounds__(256) void k_gat(
    const int* __restrict__ offs, const float4* __restrict__ rec,
    const __half* __restrict__ xl, const float* __restrict__ xr,
    const float* __restrict__ We, const float* __restrict__ att,
    const float* __restrict__ bias, float* __restrict__ hout) {
    int t = blockIdx.x * blockDim.x + threadIdx.x;
    int node = t >> 3;
    if (node >= NN) return;
    int c0 = (t & 7) * 4;  // my 4 channels; att/bias flatten to [c0+j]

    float we[FE][4];
#pragma unroll
    for (int f = 0; f < FE; ++f)
#pragma unroll
        for (int j = 0; j < 4; ++j) we[f][j] = We[f * 32 + c0 + j];
    float at0 = att[c0], at1 = att[c0 + 1], at2 = att[c0 + 2], at3 = att[c0 + 3];
    float4 xrr = *(const float4*)(xr + (size_t)node * 32 + c0);

    int start = (node == 0) ? 0 : offs[node - 1];
    int end = offs[node];

    float sm = 0.f;
    float acc0 = 0.f, acc1 = 0.f, acc2 = 0.f, acc3 = 0.f;

    for (int p = start; p < end; ++p) {
        float4 r0 = rec[(size_t)p * 2];
        float4 r1 = rec[(size_t)p * 2 + 1];
        int src = __float_as_int(r0.x);
        float2 raw = *(const float2*)(xl + (size_t)src * 32 + c0);  // 4 halfs, 8B
        __half2 h01 = *(const __half2*)&raw.x;
        __half2 h23 = *(const __half2*)&raw.y;
        float2 f01 = __half22float2(h01);
        float2 f23 = __half22float2(h23);

        float ee0, ee1, ee2, ee3;
        ee0 = r0.y * we[0][0]; ee1 = r0.y * we[0][1]; ee2 = r0.y * we[0][2]; ee3 = r0.y * we[0][3];
        ee0 = fmaf(r0.z, we[1][0], ee0); ee1 = fmaf(r0.z, we[1][1], ee1);
        ee2 = fmaf(r0.z, we[1][2], ee2); ee3 = fmaf(r0.z, we[1][3], ee3);
        ee0 = fmaf(r0.w, we[2][0], ee0); ee1 = fmaf(r0.w, we[2][1], ee1);
        ee2 = fmaf(r0.w, we[2][2], ee2); ee3 = fmaf(r0.w, we[2][3], ee3);
        ee0 = fmaf(r1.x, we[3][0], ee0); ee1 = fmaf(r1.x, we[3][1], ee1);
        ee2 = fmaf(r1.x, we[3][2], ee2); ee3 = fmaf(r1.x, we[3][3], ee3);
        ee0 = fmaf(r1.y, we[4][0], ee0); ee1 = fmaf(r1.y, we[4][1], ee1);
        ee2 = fmaf(r1.y, we[4][2], ee2); ee3 = fmaf(r1.y, we[4][3], ee3);
        ee0 = fmaf(r1.z, we[5][0], ee0); ee1 = fmaf(r1.z, we[5][1], ee1);
        ee2 = fmaf(r1.z, we[5][2], ee2); ee3 = fmaf(r1.z, we[5][3], ee3);
        ee0 = fmaf(r1.w, we[6][0], ee0); ee1 = fmaf(r1.w, we[6][1], ee1);
        ee2 = fmaf(r1.w, we[6][2], ee2); ee3 = fmaf(r1.w, we[6][3], ee3);

        float v0 = f01.x + xrr.x + ee0;
        float v1 = f01.y + xrr.y + ee1;
        float v2 = f23.x + xrr.z + ee2;
        float v3 = f23.y + xrr.w + ee3;
        v0 = v0 > 0.f ? v0 : 0.2f * v0;
        v1 = v1 > 0.f ? v1 : 0.2f * v1;
        v2 = v2 > 0.f ? v2 : 0.2f * v2;
        v3 = v3 > 0.f ? v3 : 0.2f * v3;
        float pl = fmaf(v0, at0, fmaf(v1, at1, fmaf(v2, at2, v3 * at3)));
        float L = pl + __shfl_xor(pl, 1, 64);  // full head logit (pair lanes)

        float ex = __expf(L);
        sm += ex;
        acc0 = fmaf(ex, f01.x, acc0);
        acc1 = fmaf(ex, f01.y, acc1);
        acc2 = fmaf(ex, f23.x, acc2);
        acc3 = fmaf(ex, f23.y, acc3);
    }
    float inv = 1.f / (sm + 1e-16f);
    float4 o;
    o.x = fmaf(acc0, inv, bias[c0 + 0]);
    o.y = fmaf(acc1, inv, bias[c0 + 1]);
    o.z = fmaf(acc2, inv, bias[c0 + 2]);
    o.w = fmaf(acc3, inv, bias[c0 + 3]);
    *(float4*)(hout + (size_t)node * 32 + c0) = o;
}

__global__ void k_bn_stats(const float* __restrict__ h, double* __restrict__ bn_sum,
                           double* __restrict__ bn_sumsq) {
    int c = threadIdx.x & 31;
    int row0 = (blockIdx.x * blockDim.x + threadIdx.x) >> 5;
    int rstride = (gridDim.x * blockDim.x) >> 5;
    float s = 0.f, s2 = 0.f;
    for (int n = row0; n < NN; n += rstride) {
        float v = h[(size_t)n * 32 + c];
        s += v;
        s2 = fmaf(v, v, s2);
    }
    s += __shfl_down(s, 32, 64);
    s2 += __shfl_down(s2, 32, 64);
    __shared__ float ls[4][32], ls2[4][32];
    int w = threadIdx.x >> 6;
    if ((threadIdx.x & 63) < 32) { ls[w][c] = s; ls2[w][c] = s2; }
    __syncthreads();
    if (threadIdx.x < 32) {
        float tsum = 0.f, tsq = 0.f;
        for (int i = 0; i < 4; ++i) { tsum += ls[i][threadIdx.x]; tsq += ls2[i][threadIdx.x]; }
        atomicAdd(&bn_sum[threadIdx.x], (double)tsum);
        atomicAdd(&bn_sumsq[threadIdx.x], (double)tsq);
    }
}

// wend = Wreg@Wend, c0 = breg.Wend + bend  (linear∘linear collapse)
__global__ void k_wend(const float* __restrict__ Wreg, const float* __restrict__ breg,
                       const float* __restrict__ Wend, const float* __restrict__ bend,
                       float* __restrict__ wend, float* __restrict__ c0v) {
    int t = threadIdx.x;
    if (t < 32) {
        float s = 0.f;
        for (int k = 0; k < 500; ++k) s = fmaf(Wreg[t * 500 + k], Wend[k], s);
        wend[t] = s;
    } else if (t == 32) {
        float s = 0.f;
        for (int k = 0; k < 500; ++k) s = fmaf(breg[k], Wend[k], s);
        *c0v = s + bend[0];
    }
}

__global__ void k_out(const float* __restrict__ h, const float* __restrict__ wend,
                      const float* __restrict__ c0v, float* __restrict__ out) {
    int n = blockIdx.x * blockDim.x + threadIdx.x;
    if (n >= NN) return;
    const float* r = h + (size_t)n * 32;
    float s = *c0v;
#pragma unroll
    for (int c = 0; c < 32; ++c) {
        float v = r[c];
        v = v > 0.f ? v : 0.01f * v;
        s = fmaf(v, wend[c], s);
    }
    out[n] = s;
}

extern "C" void kernel_launch(void* const* d_in, const int* in_sizes, int n_in,
                              void* d_out, int out_size, void* d_ws, size_t ws_size,
                              hipStream_t stream) {
    (void)in_sizes; (void)n_in; (void)out_size; (void)ws_size;
    const float* x    = (const float*)d_in[0];
    const int*   ei   = (const int*)d_in[1];
    const float* ea   = (const float*)d_in[2];
    const float* Wl1  = (const float*)d_in[3];
    const float* bl1  = (const float*)d_in[4];
    const float* Wr1  = (const float*)d_in[5];
    const float* br1  = (const float*)d_in[6];
    const float* We1  = (const float*)d_in[7];
    const float* att1 = (const float*)d_in[8];
    const float* b1   = (const float*)d_in[9];
    const float* Wl2  = (const float*)d_in[10];
    const float* bl2  = (const float*)d_in[11];
    const float* Wr2  = (const float*)d_in[12];
    const float* br2  = (const float*)d_in[13];
    const float* We2  = (const float*)d_in[14];
    const float* att2 = (const float*)d_in[15];
    const float* b2   = (const float*)d_in[16];
    const float* gamma= (const float*)d_in[17];
    const float* beta = (const float*)d_in[18];
    const float* Wreg = (const float*)d_in[19];
    const float* breg = (const float*)d_in[20];
    const float* Wend = (const float*)d_in[21];
    const float* bend = (const float*)d_in[22];
    float* out = (float*)d_out;

    char* w = (char*)d_ws;
    double* ea_sum   = (double*)(w + 0);
    double* bn_sum   = (double*)(w + 64);
    double* bn_sumsq = (double*)(w + 320);
    float*  ea_mean  = (float*)(w + 576);
    float*  wend     = (float*)(w + 608);
    float*  c0v      = (float*)(w + 736);
    size_t o = 1024;
    int* offs = (int*)(w + o); o += ((size_t)NN * 4 + 255) & ~(size_t)255;
    __half* xl = (__half*)(w + o); o += ((size_t)NN * 32 * 2 + 255) & ~(size_t)255;
    float* xr = (float*)(w + o); o += (size_t)NN * 32 * 4;
    float* hb = (float*)(w + o); o += (size_t)NN * 32 * 4;
    float4* rec = (float4*)(w + o); o += (size_t)EF * 8 * 4;

    hipMemsetAsync(w, 0, 1024, stream);
    hipMemsetAsync(offs, 0, (size_t)NN * 4, stream);

    const int ebl = (EF + 255) / 256;
    k_ea_sum<<<256, 256, 0, stream>>>(ea, ea_sum);
    k_ea_mean<<<1, 64, 0, stream>>>(ea_sum, ea_mean);
    k_degree<<<ebl, 256, 0, stream>>>(ei, offs);
    k_scan<<<1, 1024, 0, stream>>>(offs);
    k_fill<<<ebl, 256, 0, stream>>>(ei, ea, ea_mean, offs, rec);
    k_wend<<<1, 64, 0, stream>>>(Wreg, breg, Wend, bend, wend, c0v);

    const int xbl = (NN * 32 + 255) / 256;
    const int gbl = (NN * 8 + 255) / 256;

    // layer 1 (no BN on raw input x)
    k_xform<2, false><<<xbl, 256, 0, stream>>>(x, Wl1, bl1, Wr1, br1,
                                               bn_sum, bn_sumsq, gamma, beta, xl, xr);
    k_gat<<<gbl, 256, 0, stream>>>(offs, rec, xl, xr, We1, att1, b1, hb);

    // 2x (BN-stats -> fused BN+lrelu+xform -> layer2 GAT)
    for (int it = 0; it < 2; ++it) {
        hipMemsetAsync(w + 64, 0, 512, stream);
        k_bn_stats<<<256, 256, 0, stream>>>(hb, bn_sum, bn_sumsq);
        k_xform<32, true><<<xbl, 256, 0, stream>>>(hb, Wl2, bl2, Wr2, br2,
                                                   bn_sum, bn_sumsq, gamma, beta, xl, xr);
        k_gat<<<gbl, 256, 0, stream>>>(offs, rec, xl, xr, We2, att2, b2, hb);
    }

    k_out<<<(NN + 255) / 256, 256, 0, stream>>>(hb, wend, c0v, out);
}